// Round 10
// baseline (201.834 us; speedup 1.0000x reference)
//
#include <hip/hip_runtime.h>
#include <math.h>

#define NB 4
#define NC 4
#define NF 257
#define NFR 1024
#define NTOT (NB * NC * NF * NFR)
#define NBC (NB * NC)
#define EPSV 1e-3f
#define EPS_MODEL 1e-5f

typedef float v2f __attribute__((ext_vector_type(2)));

// Module-scope scratch: allocated at load, graph-capture safe, fully
// rewritten every call.
__device__ float g_S[NBC * NFR];  // S[b,c,n] = sum_f |X[b,c,f,n]|^2

// Wave-wide sum via DPP (VALU pipe, no LDS traffic). Lane 63 holds the sum.
__device__ __forceinline__ float dpp_red_sum(float v) {
  v += __int_as_float(__builtin_amdgcn_update_dpp(0, __float_as_int(v), 0x111, 0xf, 0xf, true)); // row_shr:1
  v += __int_as_float(__builtin_amdgcn_update_dpp(0, __float_as_int(v), 0x112, 0xf, 0xf, true)); // row_shr:2
  v += __int_as_float(__builtin_amdgcn_update_dpp(0, __float_as_int(v), 0x114, 0xf, 0xf, true)); // row_shr:4
  v += __int_as_float(__builtin_amdgcn_update_dpp(0, __float_as_int(v), 0x118, 0xf, 0xf, true)); // row_shr:8
  v += __int_as_float(__builtin_amdgcn_update_dpp(0, __float_as_int(v), 0x142, 0xa, 0xf, true)); // row_bcast:15
  v += __int_as_float(__builtin_amdgcn_update_dpp(0, __float_as_int(v), 0x143, 0xc, 0xf, true)); // row_bcast:31
  return v;
}

// ---------------------------------------------------------------------------
// K1 (new): column sums written DIRECTLY to g_S — no partial buffer, no
// second reduction kernel. Grid 16 bc x 16 n-slices = 256 blocks (full GPU).
// 256 threads = 4 freq-quarters x 64 n. For fixed f a wave reads 64
// consecutive floats (coalesced); one LDS combine of the 4 quarter partials.
// ---------------------------------------------------------------------------
__global__ __launch_bounds__(256) void k_colsum(const float* __restrict__ Xr,
                                                const float* __restrict__ Xi) {
  const int bc = blockIdx.x;              // 0..15
  const int slice = blockIdx.y;           // 0..15
  const int nloc = threadIdx.x & 63;
  const int q = threadIdx.x >> 6;         // freq quarter 0..3 (== wave id)
  const int n = slice * 64 + nloc;

  // freq ranges: q0 [0,64) q1 [64,128) q2 [128,192) q3 [192,257)
  const int f0 = q * 64;
  const int f1 = (q == 3) ? NF : (f0 + 64);

  const float* pr = Xr + (bc * NF) * NFR + n;
  const float* pi = Xi + (bc * NF) * NFR + n;
  float s = 0.f;
  for (int f = f0; f < f1; ++f) {
    float xr = pr[f * NFR];
    float xi = pi[f * NFR];
    s += xr * xr + xi * xi;
  }

  __shared__ float part[3][64];
  if (q > 0) part[q - 1][nloc] = s;
  __syncthreads();
  if (q == 0) {
    s += part[0][nloc] + part[1][nloc] + part[2][nloc];
    g_S[bc * NFR + n] = s;
  }
}

// Block-level reduction of 12 partials, 2-wave version: DPP within wave,
// one barrier, b128 LDS round-trip, double-buffered via `buf`.
__device__ __forceinline__ void block_reduce12(float* __restrict__ p,
                                               float (*red)[2][12], int buf,
                                               int lane, int wvid,
                                               float* __restrict__ s) {
#pragma unroll
  for (int k = 0; k < 12; ++k) p[k] = dpp_red_sum(p[k]);
  if (lane == 63) {
    float4* dst = reinterpret_cast<float4*>(&red[buf][wvid][0]);
    dst[0] = make_float4(p[0], p[1], p[2], p[3]);
    dst[1] = make_float4(p[4], p[5], p[6], p[7]);
    dst[2] = make_float4(p[8], p[9], p[10], p[11]);
  }
  __syncthreads();
  const float4* r = reinterpret_cast<const float4*>(&red[buf][0][0]);
#pragma unroll
  for (int k = 0; k < 3; ++k) {
    float4 a = r[k], b = r[3 + k];
    s[4 * k + 0] = a.x + b.x;
    s[4 * k + 1] = a.y + b.y;
    s[4 * k + 2] = a.z + b.z;
    s[4 * k + 3] = a.w + b.w;
  }
}

// Width-4 variant (for the s0 row-sum fold of the old k_redgp). In place.
__device__ __forceinline__ void block_reduce4(float* p, float (*red)[2][12],
                                              int buf, int lane, int wvid) {
#pragma unroll
  for (int k = 0; k < 4; ++k) p[k] = dpp_red_sum(p[k]);
  if (lane == 63) {
    float4* dst = reinterpret_cast<float4*>(&red[buf][wvid][0]);
    dst[0] = make_float4(p[0], p[1], p[2], p[3]);
  }
  __syncthreads();
  const float4* r = reinterpret_cast<const float4*>(&red[buf][0][0]);
  float4 a = r[0], b = r[3];   // wave0 at r[0..2], wave1 at r[3..5]
  p[0] = a.x + b.x;
  p[1] = a.y + b.y;
  p[2] = a.z + b.z;
  p[3] = a.w + b.w;
}

// ---------------------------------------------------------------------------
// Type-1 sweep, SRC as template param.
// Stat layout (10 live of 12 slots): [q]      num_re for c!=SRC (q = c<SRC?c:c-1)
//                                    [3+q]    num_im for c!=SRC
//                                    [6+c]    den for all c
// Diagonal numerators (c==SRC) are DEAD (v_s uses only den) -> not accumulated.
// vi[SRC]==0 is compile-time -> update for c==SRC folds to 2 fma.
// ---------------------------------------------------------------------------
template <int SRC>
__device__ __forceinline__ void t1_sweep(v2f (&xcr)[NC][4], v2f (&xci)[NC][4],
                                         v2f (&w2)[NC][4],
                                         float (&Wre)[NC][NC], float (&Wim)[NC][NC],
                                         float (*red)[2][12], int& buf,
                                         int lane, int wvid, int tid, float invN) {
  v2f p2[12];
#pragma unroll
  for (int k = 0; k < 12; ++k) p2[k] = (v2f){0.f, 0.f};
#pragma unroll
  for (int h = 0; h < 4; ++h) {
    v2f xsr = xcr[SRC][h], xsi = xci[SRC][h];
    v2f msq = xsr * xsr + xsi * xsi;
#pragma unroll
    for (int c = 0; c < NC; ++c) {
      v2f wv = w2[c][h];
      if (c != SRC) {
        const int q = (c < SRC) ? c : c - 1;
        p2[q]     += wv * (xcr[c][h] * xsr + xci[c][h] * xsi);
        p2[3 + q] += wv * (xci[c][h] * xsr - xcr[c][h] * xsi);
      }
      p2[6 + c] += wv * msq;
    }
  }
  float p[12];
#pragma unroll
  for (int k = 0; k < 12; ++k) p[k] = p2[k].x + p2[k].y;
  float s12[12];
  block_reduce12(p, red, buf, lane, wvid, s12);
  buf ^= 1;

  float vr[NC], vi[NC];
#pragma unroll
  for (int c = 0; c < NC; ++c) {
    float den = fmaxf(s12[6 + c] * invN, EPSV);
    if (c == SRC) {
      vr[c] = 1.f - __builtin_amdgcn_rsqf(den);
      vi[c] = 0.f;
    } else {
      const int q = (c < SRC) ? c : c - 1;
      float sc = invN * __builtin_amdgcn_rcpf(den);
      vr[c] = s12[q] * sc;
      vi[c] = s12[3 + q] * sc;
    }
  }
#pragma unroll
  for (int h = 0; h < 4; ++h) {
    v2f xsr = xcr[SRC][h], xsi = xci[SRC][h];
#pragma unroll
    for (int c = 0; c < NC; ++c) {
      xcr[c][h] -= xsr * vr[c] - xsi * vi[c];
      xci[c][h] -= xsi * vr[c] + xsr * vi[c];
    }
  }
  // W update parallel over 16 lanes of wave 0 (was serial in tid 0).
  // All lanes' LDS reads precede the writes in program order within the wave,
  // so reading row SRC while lane (c==SRC,j) rewrites it is race-free.
  if (tid < 16) {
    int c = tid >> 2, j = tid & 3;
    float wsr = Wre[SRC][j], wsi = Wim[SRC][j];
    float wcr = Wre[c][j],   wci = Wim[c][j];
    float vrc = (c == 0) ? vr[0] : (c == 1) ? vr[1] : (c == 2) ? vr[2] : vr[3];
    float vic = (c == 0) ? vi[0] : (c == 1) ? vi[1] : (c == 2) ? vi[2] : vi[3];
    Wre[c][j] = wcr - (vrc * wsr - vic * wsi);
    Wim[c][j] = wci - (vrc * wsi + vic * wsr);
  }
}

// ---------------------------------------------------------------------------
// Main: one block per (b,f), 128 threads (2 waves), 8 frames/thread held as
// 4x v2f pairs -> v_pk_fma_f32 codegen. Round-9 structure (measured best:
// 122.5 us) + the old k_redgp folded in: the block's 128 threads cover all
// 1024 n of each g_S row exactly once, so s0[c] is one width-4 block
// reduction; the g/P epoch recurrence is then computed locally (bit-identical
// recurrence to the old k_redgp). Pipeline is now 2 kernels, not 3.
// CRITICAL: the type-2 src loop is `#pragma unroll 1` — round 8 proved that
// unrolling it hoists all 4 srcs' window loads (96 VGPRs) above their uses,
// blowing the 128-reg cap -> 31 MB spill writes, +60 us.
// ---------------------------------------------------------------------------
__global__ __launch_bounds__(128, 2) void k_main(const float* __restrict__ Xr,
                                                 const float* __restrict__ Xi,
                                                 float* __restrict__ out, int nout) {
  const int blk = blockIdx.x;
  const int b = blk / NF, f = blk % NF;
  const int tid = threadIdx.x;            // 0..127
  const int lane = tid & 63, wvid = tid >> 6;
  const float invN = 1.f / (float)NFR;

  __shared__ float red[2][2][12];
  __shared__ float Wre[NC][NC], Wim[NC][NC];
  __shared__ float abc[8];

  v2f xcr[NC][4], xci[NC][4];
  int rowbase[NC];
#pragma unroll
  for (int c = 0; c < NC; ++c) {
    rowbase[c] = ((b * NC + c) * NF + f) * NFR;
    const float4* pr = reinterpret_cast<const float4*>(Xr + rowbase[c]);
    const float4* pi = reinterpret_cast<const float4*>(Xi + rowbase[c]);
    float4 a0 = pr[2 * tid], a1 = pr[2 * tid + 1];
    float4 b0 = pi[2 * tid], b1 = pi[2 * tid + 1];
    xcr[c][0] = (v2f){a0.x, a0.y}; xcr[c][1] = (v2f){a0.z, a0.w};
    xcr[c][2] = (v2f){a1.x, a1.y}; xcr[c][3] = (v2f){a1.z, a1.w};
    xci[c][0] = (v2f){b0.x, b0.y}; xci[c][1] = (v2f){b0.z, b0.w};
    xci[c][2] = (v2f){b1.x, b1.y}; xci[c][3] = (v2f){b1.z, b1.w};
  }
  if (tid < 16) {
    Wre[tid >> 2][tid & 3] = ((tid >> 2) == (tid & 3)) ? 1.f : 0.f;
    Wim[tid >> 2][tid & 3] = 0.f;
  }
  // W-init visibility: ordered by the first reduction's barrier.

  int buf = 0;

  // ---- folded k_redgp: s0[c] = (sum_n S[bc][n]) / (NF*NFR) ----
  float s0v[4];
  {
    float p4[4];
#pragma unroll
    for (int c = 0; c < NC; ++c) {
      const float4* ps = reinterpret_cast<const float4*>(g_S + (b * NC + c) * NFR);
      float4 S0 = ps[2 * tid], S1 = ps[2 * tid + 1];
      p4[c] = ((S0.x + S0.y) + (S0.z + S0.w)) + ((S1.x + S1.y) + (S1.z + S1.w));
    }
    block_reduce4(p4, red, buf, lane, wvid);
    buf ^= 1;
#pragma unroll
    for (int c = 0; c < NC; ++c) s0v[c] = p4[c] / (float)(NF * NFR);
  }
  float Prun[4] = {1.f, 1.f, 1.f, 1.f};

  v2f w2[NC][4];

  for (int e = 0; e < 3; ++e) {
    // ---- per-epoch weights: g/P recurrence local (was g_gP table);
    //      w = g * rcp(max(2*sqrt(S/P), eps)) ----
#pragma unroll
    for (int c = 0; c < NC; ++c) {
      float g = fmaxf(s0v[c] / Prun[c], 1e-5f);
      float sc = __builtin_amdgcn_rcpf(Prun[c]);
      Prun[c] *= g;
      const float4* ps = reinterpret_cast<const float4*>(g_S + (b * NC + c) * NFR);
      float4 S0 = ps[2 * tid], S1 = ps[2 * tid + 1];
      float sv[8] = {S0.x, S0.y, S0.z, S0.w, S1.x, S1.y, S1.z, S1.w};
      float wv[8];
#pragma unroll
      for (int j = 0; j < 8; ++j)
        wv[j] = g * __builtin_amdgcn_rcpf(fmaxf(2.f * __builtin_amdgcn_sqrtf(sv[j] * sc), EPS_MODEL));
#pragma unroll
      for (int h = 0; h < 4; ++h) w2[c][h] = (v2f){wv[2 * h], wv[2 * h + 1]};
    }

    // ================= type-1 sweeps (templated SRC) =================
    t1_sweep<0>(xcr, xci, w2, Wre, Wim, red, buf, lane, wvid, tid, invN);
    t1_sweep<1>(xcr, xci, w2, Wre, Wim, red, buf, lane, wvid, tid, invN);
    t1_sweep<2>(xcr, xci, w2, Wre, Wim, red, buf, lane, wvid, tid, invN);
    t1_sweep<3>(xcr, xci, w2, Wre, Wim, red, buf, lane, wvid, tid, invN);

    // ================= type-2 sweeps (NOT unrolled — see header note) ======
#pragma unroll 1
    for (int src = 0; src < NC; ++src) {
      const float4* pr = reinterpret_cast<const float4*>(Xr + rowbase[src]);
      const float4* pi = reinterpret_cast<const float4*>(Xi + rowbase[src]);
      // 9-frame window [8t-3 .. 8t+5] of ORIGINAL X serves both taps.
      float4 A4r = make_float4(0.f, 0.f, 0.f, 0.f), A4i = A4r;
      if (tid > 0) { A4r = pr[2 * tid - 1]; A4i = pi[2 * tid - 1]; }
      float4 B4r = pr[2 * tid], B4i = pi[2 * tid];
      float4 C4r = pr[2 * tid + 1], C4i = pi[2 * tid + 1];
      float wr[9] = {A4r.y, A4r.z, A4r.w, B4r.x, B4r.y, B4r.z, B4r.w, C4r.x, C4r.y};
      float wi[9] = {A4i.y, A4i.z, A4i.w, B4i.x, B4i.y, B4i.z, B4i.w, C4i.x, C4i.y};
#pragma unroll
      for (int tap = 0; tap < 2; ++tap) {
        v2f xs_r[4], xs_i[4];
#pragma unroll
        for (int h = 0; h < 4; ++h) {
          xs_r[h] = (v2f){wr[tap + 2 * h], wr[tap + 2 * h + 1]};
          xs_i[h] = (v2f){wi[tap + 2 * h], wi[tap + 2 * h + 1]};
        }
        v2f p2[12];
#pragma unroll
        for (int k = 0; k < 12; ++k) p2[k] = (v2f){0.f, 0.f};
#pragma unroll
        for (int h = 0; h < 4; ++h) {
          v2f xsr = xs_r[h], xsi = xs_i[h];
          v2f msq = xsr * xsr + xsi * xsi;
#pragma unroll
          for (int c = 0; c < NC; ++c) {
            v2f wv = w2[c][h];
            p2[c]     += wv * (xcr[c][h] * xsr + xci[c][h] * xsi);
            p2[4 + c] += wv * (xci[c][h] * xsr - xcr[c][h] * xsi);
            p2[8 + c] += wv * msq;
          }
        }
        float p[12];
#pragma unroll
        for (int k = 0; k < 12; ++k) p[k] = p2[k].x + p2[k].y;
        float s12[12];
        block_reduce12(p, red, buf, lane, wvid, s12);
        buf ^= 1;

        float vr[NC], vi[NC];
#pragma unroll
        for (int c = 0; c < NC; ++c) {
          float den = fmaxf(s12[8 + c], EPSV);  // SUM, not mean
          float sc = invN * __builtin_amdgcn_rcpf(den);
          vr[c] = s12[c] * sc;
          vi[c] = s12[4 + c] * sc;
        }
#pragma unroll
        for (int h = 0; h < 4; ++h) {
          v2f xsr = xs_r[h], xsi = xs_i[h];
#pragma unroll
          for (int c = 0; c < NC; ++c) {
            xcr[c][h] -= xsr * vr[c] - xsi * vi[c];
            xci[c][h] -= xsi * vr[c] + xsr * vi[c];
          }
        }
      }
    }
  }  // epochs

  // ---- solve W^T a = e1 (4x4 complex, partial pivoting), A[i][j] = W[j][i] ----
  __syncthreads();
  if (tid == 0) {
    float Ar[4][4], Ai[4][4];
    float br[4] = {1.f, 0.f, 0.f, 0.f}, bi[4] = {0.f, 0.f, 0.f, 0.f};
#pragma unroll
    for (int i = 0; i < 4; ++i)
#pragma unroll
      for (int j = 0; j < 4; ++j) {
        Ar[i][j] = Wre[j][i];
        Ai[i][j] = Wim[j][i];
      }
    for (int k = 0; k < 4; ++k) {
      int piv = k;
      float best = Ar[k][k] * Ar[k][k] + Ai[k][k] * Ai[k][k];
      for (int i = k + 1; i < 4; ++i) {
        float m = Ar[i][k] * Ar[i][k] + Ai[i][k] * Ai[i][k];
        if (m > best) { best = m; piv = i; }
      }
      if (piv != k) {
        for (int j = 0; j < 4; ++j) {
          float t = Ar[k][j]; Ar[k][j] = Ar[piv][j]; Ar[piv][j] = t;
          t = Ai[k][j]; Ai[k][j] = Ai[piv][j]; Ai[piv][j] = t;
        }
        float t = br[k]; br[k] = br[piv]; br[piv] = t;
        t = bi[k]; bi[k] = bi[piv]; bi[piv] = t;
      }
      float dr = Ar[k][k], di = Ai[k][k];
      float inv = 1.f / (dr * dr + di * di);
      for (int i = k + 1; i < 4; ++i) {
        float fr = (Ar[i][k] * dr + Ai[i][k] * di) * inv;
        float fi = (Ai[i][k] * dr - Ar[i][k] * di) * inv;
        for (int j = k; j < 4; ++j) {
          Ar[i][j] -= fr * Ar[k][j] - fi * Ai[k][j];
          Ai[i][j] -= fr * Ai[k][j] + fi * Ar[k][j];
        }
        br[i] -= fr * br[k] - fi * bi[k];
        bi[i] -= fr * bi[k] + fi * br[k];
      }
    }
    float ar[4], ai[4];
    for (int k = 3; k >= 0; --k) {
      float sr = br[k], si = bi[k];
      for (int j = k + 1; j < 4; ++j) {
        sr -= Ar[k][j] * ar[j] - Ai[k][j] * ai[j];
        si -= Ar[k][j] * ai[j] + Ai[k][j] * ar[j];
      }
      float dr = Ar[k][k], di = Ai[k][k];
      float inv = 1.f / (dr * dr + di * di);
      ar[k] = (sr * dr + si * di) * inv;
      ai[k] = (si * dr - sr * di) * inv;
    }
#pragma unroll
    for (int c = 0; c < 4; ++c) { abc[c] = ar[c]; abc[4 + c] = ai[c]; }
  }
  __syncthreads();

  // ---- output: real(Xc * a), 2x float4 per (c, thread), bounds-guarded ----
#pragma unroll
  for (int c = 0; c < NC; ++c) {
    float ar = abc[c], ai2 = abc[4 + c];
    if (rowbase[c] + 8 * tid + 7 < nout) {
      float4* po = reinterpret_cast<float4*>(out + rowbase[c]);
      v2f o0 = xcr[c][0] * ar - xci[c][0] * ai2;
      v2f o1 = xcr[c][1] * ar - xci[c][1] * ai2;
      v2f o2 = xcr[c][2] * ar - xci[c][2] * ai2;
      v2f o3 = xcr[c][3] * ar - xci[c][3] * ai2;
      po[2 * tid]     = make_float4(o0.x, o0.y, o1.x, o1.y);
      po[2 * tid + 1] = make_float4(o2.x, o2.y, o3.x, o3.y);
    }
  }
}

// ---------------------------------------------------------------------------
extern "C" void kernel_launch(void* const* d_in, const int* in_sizes, int n_in,
                              void* d_out, int out_size, void* d_ws, size_t ws_size,
                              hipStream_t stream) {
  const float* Xr = (const float*)d_in[0];
  const float* Xi = (const float*)d_in[1];
  float* out = (float*)d_out;

  dim3 g1(16, 16);  // bc x n-slice
  k_colsum<<<g1, 256, 0, stream>>>(Xr, Xi);
  k_main<<<NB * NF, 128, 0, stream>>>(Xr, Xi, out, out_size);
}

// Round 12
// 196.527 us; speedup vs baseline: 1.0270x; 1.0270x over previous
//
#include <hip/hip_runtime.h>
#include <math.h>

#define NB 4
#define NC 4
#define NF 257
#define NFR 1024
#define NTOT (NB * NC * NF * NFR)
#define NBC (NB * NC)
#define EPSV 1e-3f
#define EPS_MODEL 1e-5f
#define NCHUNK 8

typedef float v2f __attribute__((ext_vector_type(2)));

// Module-scope scratch: allocated at load, graph-capture safe, fully
// rewritten every call.
__device__ float g_Spart[NCHUNK * NBC * NFR];  // per-f-chunk partial col sums

// Wave-wide sum via DPP (VALU pipe, no LDS traffic). Lane 63 holds the sum.
__device__ __forceinline__ float dpp_red_sum(float v) {
  v += __int_as_float(__builtin_amdgcn_update_dpp(0, __float_as_int(v), 0x111, 0xf, 0xf, true)); // row_shr:1
  v += __int_as_float(__builtin_amdgcn_update_dpp(0, __float_as_int(v), 0x112, 0xf, 0xf, true)); // row_shr:2
  v += __int_as_float(__builtin_amdgcn_update_dpp(0, __float_as_int(v), 0x114, 0xf, 0xf, true)); // row_shr:4
  v += __int_as_float(__builtin_amdgcn_update_dpp(0, __float_as_int(v), 0x118, 0xf, 0xf, true)); // row_shr:8
  v += __int_as_float(__builtin_amdgcn_update_dpp(0, __float_as_int(v), 0x142, 0xa, 0xf, true)); // row_bcast:15
  v += __int_as_float(__builtin_amdgcn_update_dpp(0, __float_as_int(v), 0x143, 0xc, 0xf, true)); // row_bcast:31
  return v;
}

// ---------------------------------------------------------------------------
// K1: partial column sums, float4-vectorized (16 B/lane — the measured-fast
// shape; round 10's scalar 4 B/lane direct-write version was ~2.5x slower,
// latency-bound). Grid 16 bc x 8 f-chunks = 128 blocks, 256 threads.
// ---------------------------------------------------------------------------
__global__ __launch_bounds__(256) void k_colsum(const float* __restrict__ Xr,
                                                const float* __restrict__ Xi) {
  const int bc = blockIdx.x;              // 0..15
  const int fc = blockIdx.y;              // 0..7
  const int q = threadIdx.x;              // n-float4 index 0..255
  int f0 = fc * 33;
  int f1 = f0 + 33; if (f1 > NF) f1 = NF;
  float4 s = make_float4(0.f, 0.f, 0.f, 0.f);
  for (int f = f0; f < f1; ++f) {
    float4 a = reinterpret_cast<const float4*>(Xr + (bc * NF + f) * NFR)[q];
    float4 b = reinterpret_cast<const float4*>(Xi + (bc * NF + f) * NFR)[q];
    s.x += a.x * a.x + b.x * b.x;
    s.y += a.y * a.y + b.y * b.y;
    s.z += a.z * a.z + b.z * b.z;
    s.w += a.w * a.w + b.w * b.w;
  }
  reinterpret_cast<float4*>(g_Spart + (fc * NBC + bc) * NFR)[q] = s;
}

// Block-level reduction of 12 partials, 2-wave version: DPP within wave,
// one barrier, b128 LDS round-trip, double-buffered via `buf`.
__device__ __forceinline__ void block_reduce12(float* __restrict__ p,
                                               float (*red)[2][12], int buf,
                                               int lane, int wvid,
                                               float* __restrict__ s) {
#pragma unroll
  for (int k = 0; k < 12; ++k) p[k] = dpp_red_sum(p[k]);
  if (lane == 63) {
    float4* dst = reinterpret_cast<float4*>(&red[buf][wvid][0]);
    dst[0] = make_float4(p[0], p[1], p[2], p[3]);
    dst[1] = make_float4(p[4], p[5], p[6], p[7]);
    dst[2] = make_float4(p[8], p[9], p[10], p[11]);
  }
  __syncthreads();
  const float4* r = reinterpret_cast<const float4*>(&red[buf][0][0]);
#pragma unroll
  for (int k = 0; k < 3; ++k) {
    float4 a = r[k], b = r[3 + k];
    s[4 * k + 0] = a.x + b.x;
    s[4 * k + 1] = a.y + b.y;
    s[4 * k + 2] = a.z + b.z;
    s[4 * k + 3] = a.w + b.w;
  }
}

// Width-4 variant (for the s0 row-sum fold). In place.
__device__ __forceinline__ void block_reduce4(float* p, float (*red)[2][12],
                                              int buf, int lane, int wvid) {
#pragma unroll
  for (int k = 0; k < 4; ++k) p[k] = dpp_red_sum(p[k]);
  if (lane == 63) {
    float4* dst = reinterpret_cast<float4*>(&red[buf][wvid][0]);
    dst[0] = make_float4(p[0], p[1], p[2], p[3]);
  }
  __syncthreads();
  const float4* r = reinterpret_cast<const float4*>(&red[buf][0][0]);
  float4 a = r[0], b = r[3];   // wave0 at r[0..2], wave1 at r[3..5]
  p[0] = a.x + b.x;
  p[1] = a.y + b.y;
  p[2] = a.z + b.z;
  p[3] = a.w + b.w;
}

// ---------------------------------------------------------------------------
// Type-1 sweep, SRC as template param.
// Stat layout (10 live of 12 slots): [q]      num_re for c!=SRC (q = c<SRC?c:c-1)
//                                    [3+q]    num_im for c!=SRC
//                                    [6+c]    den for all c
// Diagonal numerators (c==SRC) are DEAD (v_s uses only den) -> not accumulated.
// vi[SRC]==0 is compile-time -> update for c==SRC folds to 2 fma.
// ---------------------------------------------------------------------------
template <int SRC>
__device__ __forceinline__ void t1_sweep(v2f (&xcr)[NC][4], v2f (&xci)[NC][4],
                                         v2f (&w2)[NC][4],
                                         float (&Wre)[NC][NC], float (&Wim)[NC][NC],
                                         float (*red)[2][12], int& buf,
                                         int lane, int wvid, int tid, float invN) {
  v2f p2[12];
#pragma unroll
  for (int k = 0; k < 12; ++k) p2[k] = (v2f){0.f, 0.f};
#pragma unroll
  for (int h = 0; h < 4; ++h) {
    v2f xsr = xcr[SRC][h], xsi = xci[SRC][h];
    v2f msq = xsr * xsr + xsi * xsi;
#pragma unroll
    for (int c = 0; c < NC; ++c) {
      v2f wv = w2[c][h];
      if (c != SRC) {
        const int q = (c < SRC) ? c : c - 1;
        p2[q]     += wv * (xcr[c][h] * xsr + xci[c][h] * xsi);
        p2[3 + q] += wv * (xci[c][h] * xsr - xcr[c][h] * xsi);
      }
      p2[6 + c] += wv * msq;
    }
  }
  float p[12];
#pragma unroll
  for (int k = 0; k < 12; ++k) p[k] = p2[k].x + p2[k].y;
  float s12[12];
  block_reduce12(p, red, buf, lane, wvid, s12);
  buf ^= 1;

  float vr[NC], vi[NC];
#pragma unroll
  for (int c = 0; c < NC; ++c) {
    float den = fmaxf(s12[6 + c] * invN, EPSV);
    if (c == SRC) {
      vr[c] = 1.f - __builtin_amdgcn_rsqf(den);
      vi[c] = 0.f;
    } else {
      const int q = (c < SRC) ? c : c - 1;
      float sc = invN * __builtin_amdgcn_rcpf(den);
      vr[c] = s12[q] * sc;
      vi[c] = s12[3 + q] * sc;
    }
  }
#pragma unroll
  for (int h = 0; h < 4; ++h) {
    v2f xsr = xcr[SRC][h], xsi = xci[SRC][h];
#pragma unroll
    for (int c = 0; c < NC; ++c) {
      xcr[c][h] -= xsr * vr[c] - xsi * vi[c];
      xci[c][h] -= xsi * vr[c] + xsr * vi[c];
    }
  }
  // W update parallel over 16 lanes of wave 0 (reads precede writes in
  // program order within the wave -> race-free).
  if (tid < 16) {
    int c = tid >> 2, j = tid & 3;
    float wsr = Wre[SRC][j], wsi = Wim[SRC][j];
    float wcr = Wre[c][j],   wci = Wim[c][j];
    float vrc = (c == 0) ? vr[0] : (c == 1) ? vr[1] : (c == 2) ? vr[2] : vr[3];
    float vic = (c == 0) ? vi[0] : (c == 1) ? vi[1] : (c == 2) ? vi[2] : vi[3];
    Wre[c][j] = wcr - (vrc * wsr - vic * wsi);
    Wim[c][j] = wci - (vrc * wsi + vic * wsr);
  }
}

// ---------------------------------------------------------------------------
// Main: one block per (b,f), 128 threads (2 waves), 8 frames/thread held as
// 4x v2f pairs. Round-9 core (measured best: 122.5 us) + folded k_redgp
// (round 10, cost-free) + the 8-chunk g_Spart combine done here at block
// start (g_Spart is 512 KB -> L2-resident across the 1028 blocks), stored to
// a 16 KB LDS buffer Sown (self-lane writes/reads, no barrier); the per-epoch
// weight prep reads Sown instead of global. Pipeline is 2 kernels with both
// in their measured-fastest shapes.
// CRITICAL (round-8 lesson): loops containing global loads are NOT unrolled
// (`#pragma unroll 1`) — unrolling hoists loads and blows the 128-reg cap.
// ---------------------------------------------------------------------------
__global__ __launch_bounds__(128, 2) void k_main(const float* __restrict__ Xr,
                                                 const float* __restrict__ Xi,
                                                 float* __restrict__ out, int nout) {
  const int blk = blockIdx.x;
  const int b = blk / NF, f = blk % NF;
  const int tid = threadIdx.x;            // 0..127
  const int lane = tid & 63, wvid = tid >> 6;
  const float invN = 1.f / (float)NFR;

  __shared__ float Sown[NC][NFR];         // 16 KB; thread owns n in [8t,8t+8)
  __shared__ float red[2][2][12];
  __shared__ float Wre[NC][NC], Wim[NC][NC];
  __shared__ float abc[8];

  v2f xcr[NC][4], xci[NC][4];
  int rowbase[NC];
#pragma unroll
  for (int c = 0; c < NC; ++c) {
    rowbase[c] = ((b * NC + c) * NF + f) * NFR;
    const float4* pr = reinterpret_cast<const float4*>(Xr + rowbase[c]);
    const float4* pi = reinterpret_cast<const float4*>(Xi + rowbase[c]);
    float4 a0 = pr[2 * tid], a1 = pr[2 * tid + 1];
    float4 b0 = pi[2 * tid], b1 = pi[2 * tid + 1];
    xcr[c][0] = (v2f){a0.x, a0.y}; xcr[c][1] = (v2f){a0.z, a0.w};
    xcr[c][2] = (v2f){a1.x, a1.y}; xcr[c][3] = (v2f){a1.z, a1.w};
    xci[c][0] = (v2f){b0.x, b0.y}; xci[c][1] = (v2f){b0.z, b0.w};
    xci[c][2] = (v2f){b1.x, b1.y}; xci[c][3] = (v2f){b1.z, b1.w};
  }
  if (tid < 16) {
    Wre[tid >> 2][tid & 3] = ((tid >> 2) == (tid & 3)) ? 1.f : 0.f;
    Wim[tid >> 2][tid & 3] = 0.f;
  }
  // W-init visibility: ordered by the first reduction's barrier.

  int buf = 0;

  // ---- combine 8 g_Spart chunks -> Sown (LDS) + s0 reduction ----
  float s0v[4];
  {
    float acc[NC][8];
#pragma unroll
    for (int c = 0; c < NC; ++c)
#pragma unroll
      for (int j = 0; j < 8; ++j) acc[c][j] = 0.f;
    // NOT unrolled: 8 iterations x 8 float4 loads; unrolling would hoist
    // 64 loads (256 regs) past the cap (round-8 lesson).
#pragma unroll 1
    for (int fc = 0; fc < NCHUNK; ++fc) {
#pragma unroll
      for (int c = 0; c < NC; ++c) {
        const float4* pp =
            reinterpret_cast<const float4*>(g_Spart + (fc * NBC + b * NC + c) * NFR);
        float4 a0 = pp[2 * tid], a1 = pp[2 * tid + 1];
        acc[c][0] += a0.x; acc[c][1] += a0.y; acc[c][2] += a0.z; acc[c][3] += a0.w;
        acc[c][4] += a1.x; acc[c][5] += a1.y; acc[c][6] += a1.z; acc[c][7] += a1.w;
      }
    }
    float p4[4];
#pragma unroll
    for (int c = 0; c < NC; ++c) {
#pragma unroll
      for (int j = 0; j < 8; ++j) Sown[c][8 * tid + j] = acc[c][j];
      p4[c] = ((acc[c][0] + acc[c][1]) + (acc[c][2] + acc[c][3])) +
              ((acc[c][4] + acc[c][5]) + (acc[c][6] + acc[c][7]));
    }
    block_reduce4(p4, red, buf, lane, wvid);
    buf ^= 1;
#pragma unroll
    for (int c = 0; c < NC; ++c) s0v[c] = p4[c] / (float)(NF * NFR);
  }
  float Prun[4] = {1.f, 1.f, 1.f, 1.f};

  v2f w2[NC][4];

  for (int e = 0; e < 3; ++e) {
    // ---- per-epoch weights from Sown (LDS, self-lane):
    //      g/P recurrence local; w = g * rcp(max(2*sqrt(S/P), eps)) ----
#pragma unroll
    for (int c = 0; c < NC; ++c) {
      float g = fmaxf(s0v[c] / Prun[c], 1e-5f);
      float sc = __builtin_amdgcn_rcpf(Prun[c]);
      Prun[c] *= g;
      float wv[8];
#pragma unroll
      for (int j = 0; j < 8; ++j) {
        float sv = Sown[c][8 * tid + j];
        wv[j] = g * __builtin_amdgcn_rcpf(fmaxf(2.f * __builtin_amdgcn_sqrtf(sv * sc), EPS_MODEL));
      }
#pragma unroll
      for (int h = 0; h < 4; ++h) w2[c][h] = (v2f){wv[2 * h], wv[2 * h + 1]};
    }

    // ================= type-1 sweeps (templated SRC) =================
    t1_sweep<0>(xcr, xci, w2, Wre, Wim, red, buf, lane, wvid, tid, invN);
    t1_sweep<1>(xcr, xci, w2, Wre, Wim, red, buf, lane, wvid, tid, invN);
    t1_sweep<2>(xcr, xci, w2, Wre, Wim, red, buf, lane, wvid, tid, invN);
    t1_sweep<3>(xcr, xci, w2, Wre, Wim, red, buf, lane, wvid, tid, invN);

    // ================= type-2 sweeps (NOT unrolled — round-8 lesson) ======
#pragma unroll 1
    for (int src = 0; src < NC; ++src) {
      const float4* pr = reinterpret_cast<const float4*>(Xr + rowbase[src]);
      const float4* pi = reinterpret_cast<const float4*>(Xi + rowbase[src]);
      // 9-frame window [8t-3 .. 8t+5] of ORIGINAL X serves both taps.
      float4 A4r = make_float4(0.f, 0.f, 0.f, 0.f), A4i = A4r;
      if (tid > 0) { A4r = pr[2 * tid - 1]; A4i = pi[2 * tid - 1]; }
      float4 B4r = pr[2 * tid], B4i = pi[2 * tid];
      float4 C4r = pr[2 * tid + 1], C4i = pi[2 * tid + 1];
      float wr[9] = {A4r.y, A4r.z, A4r.w, B4r.x, B4r.y, B4r.z, B4r.w, C4r.x, C4r.y};
      float wi[9] = {A4i.y, A4i.z, A4i.w, B4i.x, B4i.y, B4i.z, B4i.w, C4i.x, C4i.y};
#pragma unroll
      for (int tap = 0; tap < 2; ++tap) {
        v2f xs_r[4], xs_i[4];
#pragma unroll
        for (int h = 0; h < 4; ++h) {
          xs_r[h] = (v2f){wr[tap + 2 * h], wr[tap + 2 * h + 1]};
          xs_i[h] = (v2f){wi[tap + 2 * h], wi[tap + 2 * h + 1]};
        }
        v2f p2[12];
#pragma unroll
        for (int k = 0; k < 12; ++k) p2[k] = (v2f){0.f, 0.f};
#pragma unroll
        for (int h = 0; h < 4; ++h) {
          v2f xsr = xs_r[h], xsi = xs_i[h];
          v2f msq = xsr * xsr + xsi * xsi;
#pragma unroll
          for (int c = 0; c < NC; ++c) {
            v2f wv = w2[c][h];
            p2[c]     += wv * (xcr[c][h] * xsr + xci[c][h] * xsi);
            p2[4 + c] += wv * (xci[c][h] * xsr - xcr[c][h] * xsi);
            p2[8 + c] += wv * msq;
          }
        }
        float p[12];
#pragma unroll
        for (int k = 0; k < 12; ++k) p[k] = p2[k].x + p2[k].y;
        float s12[12];
        block_reduce12(p, red, buf, lane, wvid, s12);
        buf ^= 1;

        float vr[NC], vi[NC];
#pragma unroll
        for (int c = 0; c < NC; ++c) {
          float den = fmaxf(s12[8 + c], EPSV);  // SUM, not mean
          float sc = invN * __builtin_amdgcn_rcpf(den);
          vr[c] = s12[c] * sc;
          vi[c] = s12[4 + c] * sc;
        }
#pragma unroll
        for (int h = 0; h < 4; ++h) {
          v2f xsr = xs_r[h], xsi = xs_i[h];
#pragma unroll
          for (int c = 0; c < NC; ++c) {
            xcr[c][h] -= xsr * vr[c] - xsi * vi[c];
            xci[c][h] -= xsi * vr[c] + xsr * vi[c];
          }
        }
      }
    }
  }  // epochs

  // ---- solve W^T a = e1 (4x4 complex, partial pivoting), A[i][j] = W[j][i] ----
  __syncthreads();
  if (tid == 0) {
    float Ar[4][4], Ai[4][4];
    float br[4] = {1.f, 0.f, 0.f, 0.f}, bi[4] = {0.f, 0.f, 0.f, 0.f};
#pragma unroll
    for (int i = 0; i < 4; ++i)
#pragma unroll
      for (int j = 0; j < 4; ++j) {
        Ar[i][j] = Wre[j][i];
        Ai[i][j] = Wim[j][i];
      }
    for (int k = 0; k < 4; ++k) {
      int piv = k;
      float best = Ar[k][k] * Ar[k][k] + Ai[k][k] * Ai[k][k];
      for (int i = k + 1; i < 4; ++i) {
        float m = Ar[i][k] * Ar[i][k] + Ai[i][k] * Ai[i][k];
        if (m > best) { best = m; piv = i; }
      }
      if (piv != k) {
        for (int j = 0; j < 4; ++j) {
          float t = Ar[k][j]; Ar[k][j] = Ar[piv][j]; Ar[piv][j] = t;
          t = Ai[k][j]; Ai[k][j] = Ai[piv][j]; Ai[piv][j] = t;
        }
        float t = br[k]; br[k] = br[piv]; br[piv] = t;
        t = bi[k]; bi[k] = bi[piv]; bi[piv] = t;
      }
      float dr = Ar[k][k], di = Ai[k][k];
      float inv = 1.f / (dr * dr + di * di);
      for (int i = k + 1; i < 4; ++i) {
        float fr = (Ar[i][k] * dr + Ai[i][k] * di) * inv;
        float fi = (Ai[i][k] * dr - Ar[i][k] * di) * inv;
        for (int j = k; j < 4; ++j) {
          Ar[i][j] -= fr * Ar[k][j] - fi * Ai[k][j];
          Ai[i][j] -= fr * Ai[k][j] + fi * Ar[k][j];
        }
        br[i] -= fr * br[k] - fi * bi[k];
        bi[i] -= fr * bi[k] + fi * br[k];
      }
    }
    float ar[4], ai[4];
    for (int k = 3; k >= 0; --k) {
      float sr = br[k], si = bi[k];
      for (int j = k + 1; j < 4; ++j) {
        sr -= Ar[k][j] * ar[j] - Ai[k][j] * ai[j];
        si -= Ar[k][j] * ai[j] + Ai[k][j] * ar[j];
      }
      float dr = Ar[k][k], di = Ai[k][k];
      float inv = 1.f / (dr * dr + di * di);
      ar[k] = (sr * dr + si * di) * inv;
      ai[k] = (si * dr - sr * di) * inv;
    }
#pragma unroll
    for (int c = 0; c < 4; ++c) { abc[c] = ar[c]; abc[4 + c] = ai[c]; }
  }
  __syncthreads();

  // ---- output: real(Xc * a), 2x float4 per (c, thread), bounds-guarded ----
#pragma unroll
  for (int c = 0; c < NC; ++c) {
    float ar = abc[c], ai2 = abc[4 + c];
    if (rowbase[c] + 8 * tid + 7 < nout) {
      float4* po = reinterpret_cast<float4*>(out + rowbase[c]);
      v2f o0 = xcr[c][0] * ar - xci[c][0] * ai2;
      v2f o1 = xcr[c][1] * ar - xci[c][1] * ai2;
      v2f o2 = xcr[c][2] * ar - xci[c][2] * ai2;
      v2f o3 = xcr[c][3] * ar - xci[c][3] * ai2;
      po[2 * tid]     = make_float4(o0.x, o0.y, o1.x, o1.y);
      po[2 * tid + 1] = make_float4(o2.x, o2.y, o3.x, o3.y);
    }
  }
}

// ---------------------------------------------------------------------------
extern "C" void kernel_launch(void* const* d_in, const int* in_sizes, int n_in,
                              void* d_out, int out_size, void* d_ws, size_t ws_size,
                              hipStream_t stream) {
  const float* Xr = (const float*)d_in[0];
  const float* Xi = (const float*)d_in[1];
  float* out = (float*)d_out;

  dim3 g1(16, NCHUNK);  // bc x f-chunk
  k_colsum<<<g1, 256, 0, stream>>>(Xr, Xi);
  k_main<<<NB * NF, 128, 0, stream>>>(Xr, Xi, out, out_size);
}

// Round 13
// 196.133 us; speedup vs baseline: 1.0291x; 1.0020x over previous
//
#include <hip/hip_runtime.h>
#include <math.h>

#define NB 4
#define NC 4
#define NF 257
#define NFR 1024
#define NTOT (NB * NC * NF * NFR)
#define NBC (NB * NC)
#define EPSV 1e-3f
#define EPS_MODEL 1e-5f
#define NCHUNK 8

typedef float v2f __attribute__((ext_vector_type(2)));

// Module-scope scratch: allocated at load, graph-capture safe, fully
// rewritten every call.
__device__ float g_Spart[NCHUNK * NBC * NFR];  // per-f-chunk partial col sums

// Wave-wide sum via DPP (VALU pipe, no LDS traffic). Lane 63 holds the sum.
__device__ __forceinline__ float dpp_red_sum(float v) {
  v += __int_as_float(__builtin_amdgcn_update_dpp(0, __float_as_int(v), 0x111, 0xf, 0xf, true)); // row_shr:1
  v += __int_as_float(__builtin_amdgcn_update_dpp(0, __float_as_int(v), 0x112, 0xf, 0xf, true)); // row_shr:2
  v += __int_as_float(__builtin_amdgcn_update_dpp(0, __float_as_int(v), 0x114, 0xf, 0xf, true)); // row_shr:4
  v += __int_as_float(__builtin_amdgcn_update_dpp(0, __float_as_int(v), 0x118, 0xf, 0xf, true)); // row_shr:8
  v += __int_as_float(__builtin_amdgcn_update_dpp(0, __float_as_int(v), 0x142, 0xa, 0xf, true)); // row_bcast:15
  v += __int_as_float(__builtin_amdgcn_update_dpp(0, __float_as_int(v), 0x143, 0xc, 0xf, true)); // row_bcast:31
  return v;
}

// ---------------------------------------------------------------------------
// K1: partial column sums, float4-vectorized (16 B/lane — the measured-fast
// shape). Grid 16 bc x 8 f-chunks = 128 blocks, 256 threads.
// ---------------------------------------------------------------------------
__global__ __launch_bounds__(256) void k_colsum(const float* __restrict__ Xr,
                                                const float* __restrict__ Xi) {
  const int bc = blockIdx.x;              // 0..15
  const int fc = blockIdx.y;              // 0..7
  const int q = threadIdx.x;              // n-float4 index 0..255
  int f0 = fc * 33;
  int f1 = f0 + 33; if (f1 > NF) f1 = NF;
  float4 s = make_float4(0.f, 0.f, 0.f, 0.f);
  for (int f = f0; f < f1; ++f) {
    float4 a = reinterpret_cast<const float4*>(Xr + (bc * NF + f) * NFR)[q];
    float4 b = reinterpret_cast<const float4*>(Xi + (bc * NF + f) * NFR)[q];
    s.x += a.x * a.x + b.x * b.x;
    s.y += a.y * a.y + b.y * b.y;
    s.z += a.z * a.z + b.z * b.z;
    s.w += a.w * a.w + b.w * b.w;
  }
  reinterpret_cast<float4*>(g_Spart + (fc * NBC + bc) * NFR)[q] = s;
}

// Block-level reduction of 12 partials, 2-wave version: DPP within wave,
// one barrier, b128 LDS round-trip, double-buffered via `buf`.
__device__ __forceinline__ void block_reduce12(float* __restrict__ p,
                                               float (*red)[2][12], int buf,
                                               int lane, int wvid,
                                               float* __restrict__ s) {
#pragma unroll
  for (int k = 0; k < 12; ++k) p[k] = dpp_red_sum(p[k]);
  if (lane == 63) {
    float4* dst = reinterpret_cast<float4*>(&red[buf][wvid][0]);
    dst[0] = make_float4(p[0], p[1], p[2], p[3]);
    dst[1] = make_float4(p[4], p[5], p[6], p[7]);
    dst[2] = make_float4(p[8], p[9], p[10], p[11]);
  }
  __syncthreads();
  const float4* r = reinterpret_cast<const float4*>(&red[buf][0][0]);
#pragma unroll
  for (int k = 0; k < 3; ++k) {
    float4 a = r[k], b = r[3 + k];
    s[4 * k + 0] = a.x + b.x;
    s[4 * k + 1] = a.y + b.y;
    s[4 * k + 2] = a.z + b.z;
    s[4 * k + 3] = a.w + b.w;
  }
}

// Width-4 variant (for the s0 row-sum fold). In place.
__device__ __forceinline__ void block_reduce4(float* p, float (*red)[2][12],
                                              int buf, int lane, int wvid) {
#pragma unroll
  for (int k = 0; k < 4; ++k) p[k] = dpp_red_sum(p[k]);
  if (lane == 63) {
    float4* dst = reinterpret_cast<float4*>(&red[buf][wvid][0]);
    dst[0] = make_float4(p[0], p[1], p[2], p[3]);
  }
  __syncthreads();
  const float4* r = reinterpret_cast<const float4*>(&red[buf][0][0]);
  float4 a = r[0], b = r[3];   // wave0 at r[0..2], wave1 at r[3..5]
  p[0] = a.x + b.x;
  p[1] = a.y + b.y;
  p[2] = a.z + b.z;
  p[3] = a.w + b.w;
}

// ---------------------------------------------------------------------------
// Type-1 sweep, SRC as template param.
// Stat layout (10 live of 12 slots): [q]      num_re for c!=SRC (q = c<SRC?c:c-1)
//                                    [3+q]    num_im for c!=SRC
//                                    [6+c]    den for all c
// Diagonal numerators (c==SRC) are DEAD (v_s uses only den) -> not accumulated.
// vi[SRC]==0 is compile-time -> update for c==SRC folds to 2 fma.
// ---------------------------------------------------------------------------
template <int SRC>
__device__ __forceinline__ void t1_sweep(v2f (&xcr)[NC][4], v2f (&xci)[NC][4],
                                         v2f (&w2)[NC][4],
                                         float (&Wre)[NC][NC], float (&Wim)[NC][NC],
                                         float (*red)[2][12], int& buf,
                                         int lane, int wvid, int tid, float invN) {
  v2f p2[12];
#pragma unroll
  for (int k = 0; k < 12; ++k) p2[k] = (v2f){0.f, 0.f};
#pragma unroll
  for (int h = 0; h < 4; ++h) {
    v2f xsr = xcr[SRC][h], xsi = xci[SRC][h];
    v2f msq = xsr * xsr + xsi * xsi;
#pragma unroll
    for (int c = 0; c < NC; ++c) {
      v2f wv = w2[c][h];
      if (c != SRC) {
        const int q = (c < SRC) ? c : c - 1;
        p2[q]     += wv * (xcr[c][h] * xsr + xci[c][h] * xsi);
        p2[3 + q] += wv * (xci[c][h] * xsr - xcr[c][h] * xsi);
      }
      p2[6 + c] += wv * msq;
    }
  }
  float p[12];
#pragma unroll
  for (int k = 0; k < 12; ++k) p[k] = p2[k].x + p2[k].y;
  float s12[12];
  block_reduce12(p, red, buf, lane, wvid, s12);
  buf ^= 1;

  float vr[NC], vi[NC];
#pragma unroll
  for (int c = 0; c < NC; ++c) {
    float den = fmaxf(s12[6 + c] * invN, EPSV);
    if (c == SRC) {
      vr[c] = 1.f - __builtin_amdgcn_rsqf(den);
      vi[c] = 0.f;
    } else {
      const int q = (c < SRC) ? c : c - 1;
      float sc = invN * __builtin_amdgcn_rcpf(den);
      vr[c] = s12[q] * sc;
      vi[c] = s12[3 + q] * sc;
    }
  }
#pragma unroll
  for (int h = 0; h < 4; ++h) {
    v2f xsr = xcr[SRC][h], xsi = xci[SRC][h];
#pragma unroll
    for (int c = 0; c < NC; ++c) {
      xcr[c][h] -= xsr * vr[c] - xsi * vi[c];
      xci[c][h] -= xsi * vr[c] + xsr * vi[c];
    }
  }
  // W update parallel over 16 lanes of wave 0 (reads precede writes in
  // program order within the wave -> race-free).
  if (tid < 16) {
    int c = tid >> 2, j = tid & 3;
    float wsr = Wre[SRC][j], wsi = Wim[SRC][j];
    float wcr = Wre[c][j],   wci = Wim[c][j];
    float vrc = (c == 0) ? vr[0] : (c == 1) ? vr[1] : (c == 2) ? vr[2] : vr[3];
    float vic = (c == 0) ? vi[0] : (c == 1) ? vi[1] : (c == 2) ? vi[2] : vi[3];
    Wre[c][j] = wcr - (vrc * wsr - vic * wsi);
    Wim[c][j] = wci - (vrc * wsi + vic * wsr);
  }
}

// ---------------------------------------------------------------------------
// Main: one block per (b,f), 128 threads (2 waves), 8 frames/thread held as
// 4x v2f pairs. Round-12 base with two repairs:
//  (1) Sown transposed to [NC][8][128] (Sown[c][j][tid]) — lane stride 4 B,
//      2 lanes/bank = conflict-free. R12's [c][8t+j] layout hit banks
//      {0,8,16,24} only -> 329K conflict cycles/dispatch.
//  (2) t2 window software-prefetch one src ahead: wr/wi extracted from a
//      persistent register buffer, next src's 6 float4 loads issued
//      immediately after — L3 latency hides under the stage's ~4000 cy of
//      accumulate/DPP/barrier instead of serializing at stage entry. ONE
//      window in flight (+24 VGPR), not round 8's all-4 hoist (spill).
// __launch_bounds__(128, 1): cap 256 (live set ~135 > the (128,2) cap of
// 128). Residency stays grid-limited (~4 blocks/CU) — unchanged.
// CRITICAL (round-8 lesson): loops containing global loads stay unroll 1.
// ---------------------------------------------------------------------------
__global__ __launch_bounds__(128, 1) void k_main(const float* __restrict__ Xr,
                                                 const float* __restrict__ Xi,
                                                 float* __restrict__ out, int nout) {
  const int blk = blockIdx.x;
  const int b = blk / NF, f = blk % NF;
  const int tid = threadIdx.x;            // 0..127
  const int lane = tid & 63, wvid = tid >> 6;
  const float invN = 1.f / (float)NFR;

  __shared__ float Sown[NC][8][128];      // 16 KB; [c][j][tid], conflict-free
  __shared__ float red[2][2][12];
  __shared__ float Wre[NC][NC], Wim[NC][NC];
  __shared__ float abc[8];

  v2f xcr[NC][4], xci[NC][4];
  int rowbase[NC];
#pragma unroll
  for (int c = 0; c < NC; ++c) {
    rowbase[c] = ((b * NC + c) * NF + f) * NFR;
    const float4* pr = reinterpret_cast<const float4*>(Xr + rowbase[c]);
    const float4* pi = reinterpret_cast<const float4*>(Xi + rowbase[c]);
    float4 a0 = pr[2 * tid], a1 = pr[2 * tid + 1];
    float4 b0 = pi[2 * tid], b1 = pi[2 * tid + 1];
    xcr[c][0] = (v2f){a0.x, a0.y}; xcr[c][1] = (v2f){a0.z, a0.w};
    xcr[c][2] = (v2f){a1.x, a1.y}; xcr[c][3] = (v2f){a1.z, a1.w};
    xci[c][0] = (v2f){b0.x, b0.y}; xci[c][1] = (v2f){b0.z, b0.w};
    xci[c][2] = (v2f){b1.x, b1.y}; xci[c][3] = (v2f){b1.z, b1.w};
  }
  if (tid < 16) {
    Wre[tid >> 2][tid & 3] = ((tid >> 2) == (tid & 3)) ? 1.f : 0.f;
    Wim[tid >> 2][tid & 3] = 0.f;
  }
  // W-init visibility: ordered by the first reduction's barrier.

  int buf = 0;

  // ---- combine 8 g_Spart chunks -> Sown (LDS) + s0 reduction ----
  float s0v[4];
  {
    float acc[NC][8];
#pragma unroll
    for (int c = 0; c < NC; ++c)
#pragma unroll
      for (int j = 0; j < 8; ++j) acc[c][j] = 0.f;
    // NOT unrolled: 8 iterations x 8 float4 loads; unrolling would hoist
    // 64 loads (256 regs) past the cap (round-8 lesson).
#pragma unroll 1
    for (int fc = 0; fc < NCHUNK; ++fc) {
#pragma unroll
      for (int c = 0; c < NC; ++c) {
        const float4* pp =
            reinterpret_cast<const float4*>(g_Spart + (fc * NBC + b * NC + c) * NFR);
        float4 a0 = pp[2 * tid], a1 = pp[2 * tid + 1];
        acc[c][0] += a0.x; acc[c][1] += a0.y; acc[c][2] += a0.z; acc[c][3] += a0.w;
        acc[c][4] += a1.x; acc[c][5] += a1.y; acc[c][6] += a1.z; acc[c][7] += a1.w;
      }
    }
    float p4[4];
#pragma unroll
    for (int c = 0; c < NC; ++c) {
#pragma unroll
      for (int j = 0; j < 8; ++j) Sown[c][j][tid] = acc[c][j];
      p4[c] = ((acc[c][0] + acc[c][1]) + (acc[c][2] + acc[c][3])) +
              ((acc[c][4] + acc[c][5]) + (acc[c][6] + acc[c][7]));
    }
    block_reduce4(p4, red, buf, lane, wvid);
    buf ^= 1;
#pragma unroll
    for (int c = 0; c < NC; ++c) s0v[c] = p4[c] / (float)(NF * NFR);
  }
  float Prun[4] = {1.f, 1.f, 1.f, 1.f};

  v2f w2[NC][4];

  // ---- t2 window prefetch buffer: preload src-0's 9-frame window ----
  float4 nA4r, nA4i, nB4r, nB4i, nC4r, nC4i;
  {
    const float4* pr0 = reinterpret_cast<const float4*>(Xr + rowbase[0]);
    const float4* pi0 = reinterpret_cast<const float4*>(Xi + rowbase[0]);
    nA4r = make_float4(0.f, 0.f, 0.f, 0.f); nA4i = nA4r;
    if (tid > 0) { nA4r = pr0[2 * tid - 1]; nA4i = pi0[2 * tid - 1]; }
    nB4r = pr0[2 * tid];     nB4i = pi0[2 * tid];
    nC4r = pr0[2 * tid + 1]; nC4i = pi0[2 * tid + 1];
  }

  for (int e = 0; e < 3; ++e) {
    // ---- per-epoch weights from Sown (LDS, conflict-free):
    //      g/P recurrence local; w = g * rcp(max(2*sqrt(S/P), eps)) ----
#pragma unroll
    for (int c = 0; c < NC; ++c) {
      float g = fmaxf(s0v[c] / Prun[c], 1e-5f);
      float sc = __builtin_amdgcn_rcpf(Prun[c]);
      Prun[c] *= g;
      float wv[8];
#pragma unroll
      for (int j = 0; j < 8; ++j) {
        float sv = Sown[c][j][tid];
        wv[j] = g * __builtin_amdgcn_rcpf(fmaxf(2.f * __builtin_amdgcn_sqrtf(sv * sc), EPS_MODEL));
      }
#pragma unroll
      for (int h = 0; h < 4; ++h) w2[c][h] = (v2f){wv[2 * h], wv[2 * h + 1]};
    }

    // ================= type-1 sweeps (templated SRC) =================
    t1_sweep<0>(xcr, xci, w2, Wre, Wim, red, buf, lane, wvid, tid, invN);
    t1_sweep<1>(xcr, xci, w2, Wre, Wim, red, buf, lane, wvid, tid, invN);
    t1_sweep<2>(xcr, xci, w2, Wre, Wim, red, buf, lane, wvid, tid, invN);
    t1_sweep<3>(xcr, xci, w2, Wre, Wim, red, buf, lane, wvid, tid, invN);

    // ======== type-2 sweeps (unroll 1; window double-buffered) ========
#pragma unroll 1
    for (int src = 0; src < NC; ++src) {
      // Extract the CURRENT window from the prefetch buffer.
      float wr[9] = {nA4r.y, nA4r.z, nA4r.w, nB4r.x, nB4r.y, nB4r.z, nB4r.w, nC4r.x, nC4r.y};
      float wi[9] = {nA4i.y, nA4i.z, nA4i.w, nB4i.x, nB4i.y, nB4i.z, nB4i.w, nC4i.x, nC4i.y};
      // Issue NEXT window's loads now — latency hides under this stage's
      // accumulate + DPP + barrier (~4000 cy >> L3 ~300 cy). (src+1)&3
      // wraps to src 0 for the next epoch (last epoch's wrap is dead but
      // harmless). Only ONE window in flight: +24 VGPR, no spill.
      {
        const int nsrc = (src + 1) & 3;
        const float4* prn = reinterpret_cast<const float4*>(Xr + rowbase[nsrc]);
        const float4* pin = reinterpret_cast<const float4*>(Xi + rowbase[nsrc]);
        nA4r = make_float4(0.f, 0.f, 0.f, 0.f); nA4i = nA4r;
        if (tid > 0) { nA4r = prn[2 * tid - 1]; nA4i = pin[2 * tid - 1]; }
        nB4r = prn[2 * tid];     nB4i = pin[2 * tid];
        nC4r = prn[2 * tid + 1]; nC4i = pin[2 * tid + 1];
      }
#pragma unroll
      for (int tap = 0; tap < 2; ++tap) {
        v2f xs_r[4], xs_i[4];
#pragma unroll
        for (int h = 0; h < 4; ++h) {
          xs_r[h] = (v2f){wr[tap + 2 * h], wr[tap + 2 * h + 1]};
          xs_i[h] = (v2f){wi[tap + 2 * h], wi[tap + 2 * h + 1]};
        }
        v2f p2[12];
#pragma unroll
        for (int k = 0; k < 12; ++k) p2[k] = (v2f){0.f, 0.f};
#pragma unroll
        for (int h = 0; h < 4; ++h) {
          v2f xsr = xs_r[h], xsi = xs_i[h];
          v2f msq = xsr * xsr + xsi * xsi;
#pragma unroll
          for (int c = 0; c < NC; ++c) {
            v2f wv = w2[c][h];
            p2[c]     += wv * (xcr[c][h] * xsr + xci[c][h] * xsi);
            p2[4 + c] += wv * (xci[c][h] * xsr - xcr[c][h] * xsi);
            p2[8 + c] += wv * msq;
          }
        }
        float p[12];
#pragma unroll
        for (int k = 0; k < 12; ++k) p[k] = p2[k].x + p2[k].y;
        float s12[12];
        block_reduce12(p, red, buf, lane, wvid, s12);
        buf ^= 1;

        float vr[NC], vi[NC];
#pragma unroll
        for (int c = 0; c < NC; ++c) {
          float den = fmaxf(s12[8 + c], EPSV);  // SUM, not mean
          float sc = invN * __builtin_amdgcn_rcpf(den);
          vr[c] = s12[c] * sc;
          vi[c] = s12[4 + c] * sc;
        }
#pragma unroll
        for (int h = 0; h < 4; ++h) {
          v2f xsr = xs_r[h], xsi = xs_i[h];
#pragma unroll
          for (int c = 0; c < NC; ++c) {
            xcr[c][h] -= xsr * vr[c] - xsi * vi[c];
            xci[c][h] -= xsi * vr[c] + xsr * vi[c];
          }
        }
      }
    }
  }  // epochs

  // ---- solve W^T a = e1 (4x4 complex, partial pivoting), A[i][j] = W[j][i] ----
  __syncthreads();
  if (tid == 0) {
    float Ar[4][4], Ai[4][4];
    float br[4] = {1.f, 0.f, 0.f, 0.f}, bi[4] = {0.f, 0.f, 0.f, 0.f};
#pragma unroll
    for (int i = 0; i < 4; ++i)
#pragma unroll
      for (int j = 0; j < 4; ++j) {
        Ar[i][j] = Wre[j][i];
        Ai[i][j] = Wim[j][i];
      }
    for (int k = 0; k < 4; ++k) {
      int piv = k;
      float best = Ar[k][k] * Ar[k][k] + Ai[k][k] * Ai[k][k];
      for (int i = k + 1; i < 4; ++i) {
        float m = Ar[i][k] * Ar[i][k] + Ai[i][k] * Ai[i][k];
        if (m > best) { best = m; piv = i; }
      }
      if (piv != k) {
        for (int j = 0; j < 4; ++j) {
          float t = Ar[k][j]; Ar[k][j] = Ar[piv][j]; Ar[piv][j] = t;
          t = Ai[k][j]; Ai[k][j] = Ai[piv][j]; Ai[piv][j] = t;
        }
        float t = br[k]; br[k] = br[piv]; br[piv] = t;
        t = bi[k]; bi[k] = bi[piv]; bi[piv] = t;
      }
      float dr = Ar[k][k], di = Ai[k][k];
      float inv = 1.f / (dr * dr + di * di);
      for (int i = k + 1; i < 4; ++i) {
        float fr = (Ar[i][k] * dr + Ai[i][k] * di) * inv;
        float fi = (Ai[i][k] * dr - Ar[i][k] * di) * inv;
        for (int j = k; j < 4; ++j) {
          Ar[i][j] -= fr * Ar[k][j] - fi * Ai[k][j];
          Ai[i][j] -= fr * Ai[k][j] + fi * Ar[k][j];
        }
        br[i] -= fr * br[k] - fi * bi[k];
        bi[i] -= fr * bi[k] + fi * br[k];
      }
    }
    float ar[4], ai[4];
    for (int k = 3; k >= 0; --k) {
      float sr = br[k], si = bi[k];
      for (int j = k + 1; j < 4; ++j) {
        sr -= Ar[k][j] * ar[j] - Ai[k][j] * ai[j];
        si -= Ar[k][j] * ai[j] + Ai[k][j] * ar[j];
      }
      float dr = Ar[k][k], di = Ai[k][k];
      float inv = 1.f / (dr * dr + di * di);
      ar[k] = (sr * dr + si * di) * inv;
      ai[k] = (si * dr - sr * di) * inv;
    }
#pragma unroll
    for (int c = 0; c < 4; ++c) { abc[c] = ar[c]; abc[4 + c] = ai[c]; }
  }
  __syncthreads();

  // ---- output: real(Xc * a), 2x float4 per (c, thread), bounds-guarded ----
#pragma unroll
  for (int c = 0; c < NC; ++c) {
    float ar = abc[c], ai2 = abc[4 + c];
    if (rowbase[c] + 8 * tid + 7 < nout) {
      float4* po = reinterpret_cast<float4*>(out + rowbase[c]);
      v2f o0 = xcr[c][0] * ar - xci[c][0] * ai2;
      v2f o1 = xcr[c][1] * ar - xci[c][1] * ai2;
      v2f o2 = xcr[c][2] * ar - xci[c][2] * ai2;
      v2f o3 = xcr[c][3] * ar - xci[c][3] * ai2;
      po[2 * tid]     = make_float4(o0.x, o0.y, o1.x, o1.y);
      po[2 * tid + 1] = make_float4(o2.x, o2.y, o3.x, o3.y);
    }
  }
}

// ---------------------------------------------------------------------------
extern "C" void kernel_launch(void* const* d_in, const int* in_sizes, int n_in,
                              void* d_out, int out_size, void* d_ws, size_t ws_size,
                              hipStream_t stream) {
  const float* Xr = (const float*)d_in[0];
  const float* Xi = (const float*)d_in[1];
  float* out = (float*)d_out;

  dim3 g1(16, NCHUNK);  // bc x f-chunk
  k_colsum<<<g1, 256, 0, stream>>>(Xr, Xi);
  k_main<<<NB * NF, 128, 0, stream>>>(Xr, Xi, out, out_size);
}

// Round 14
// 189.857 us; speedup vs baseline: 1.0631x; 1.0331x over previous
//
#include <hip/hip_runtime.h>
#include <math.h>

#define NB 4
#define NC 4
#define NF 257
#define NFR 1024
#define NTOT (NB * NC * NF * NFR)
#define NBC (NB * NC)
#define EPSV 1e-3f
#define EPS_MODEL 1e-5f
#define NCHUNK 32

typedef float v2f __attribute__((ext_vector_type(2)));

// Module-scope scratch: allocated at load, graph-capture safe, fully
// rewritten every call.
__device__ float g_Spart[NCHUNK * NBC * NFR];  // partial column sums
__device__ float g_S[NBC * NFR];               // S[b,c,n] = sum_f |X[b,c,f,n]|^2
__device__ float g_gP[96];                     // g_e, P_e per (b,c), e=0..2

// Wave-wide sum via DPP (VALU pipe, no LDS traffic). Lane 63 holds the sum.
__device__ __forceinline__ float dpp_red_sum(float v) {
  v += __int_as_float(__builtin_amdgcn_update_dpp(0, __float_as_int(v), 0x111, 0xf, 0xf, true)); // row_shr:1
  v += __int_as_float(__builtin_amdgcn_update_dpp(0, __float_as_int(v), 0x112, 0xf, 0xf, true)); // row_shr:2
  v += __int_as_float(__builtin_amdgcn_update_dpp(0, __float_as_int(v), 0x114, 0xf, 0xf, true)); // row_shr:4
  v += __int_as_float(__builtin_amdgcn_update_dpp(0, __float_as_int(v), 0x118, 0xf, 0xf, true)); // row_shr:8
  v += __int_as_float(__builtin_amdgcn_update_dpp(0, __float_as_int(v), 0x142, 0xa, 0xf, true)); // row_bcast:15
  v += __int_as_float(__builtin_amdgcn_update_dpp(0, __float_as_int(v), 0x143, 0xc, 0xf, true)); // row_bcast:31
  return v;
}

// ---------------------------------------------------------------------------
// K1: partial column sums, float4-vectorized, 512 blocks (full GPU).
// ---------------------------------------------------------------------------
__global__ __launch_bounds__(256) void k_colsum(const float* __restrict__ Xr,
                                                const float* __restrict__ Xi) {
  int u = blockIdx.x * 256 + threadIdx.x;  // bc*256 + q
  int fc = blockIdx.y;
  int f0 = fc * 9;
  int f1 = f0 + 9; if (f1 > NF) f1 = NF;
  int bc = u >> 8, q = u & 255;
  float4 s = make_float4(0.f, 0.f, 0.f, 0.f);
  for (int f = f0; f < f1; ++f) {
    float4 a = reinterpret_cast<const float4*>(Xr + (bc * NF + f) * NFR)[q];
    float4 b = reinterpret_cast<const float4*>(Xi + (bc * NF + f) * NFR)[q];
    s.x += a.x * a.x + b.x * b.x;
    s.y += a.y * a.y + b.y * b.y;
    s.z += a.z * a.z + b.z * b.z;
    s.w += a.w * a.w + b.w * b.w;
  }
  reinterpret_cast<float4*>(g_Spart + fc * (NBC * NFR) + bc * NFR)[q] = s;
}

// ---------------------------------------------------------------------------
// K2 (fused): reduce 32 partials -> g_S; block-reduce to s0; g_e/P_e table.
// ---------------------------------------------------------------------------
__global__ __launch_bounds__(256) void k_redgp() {
  int bc = blockIdx.x, tid = threadIdx.x;
  float4 s = make_float4(0.f, 0.f, 0.f, 0.f);
#pragma unroll
  for (int fc = 0; fc < NCHUNK; ++fc) {
    float4 a = reinterpret_cast<const float4*>(g_Spart + fc * (NBC * NFR) + bc * NFR)[tid];
    s.x += a.x; s.y += a.y; s.z += a.z; s.w += a.w;
  }
  reinterpret_cast<float4*>(g_S + bc * NFR)[tid] = s;
  float p = dpp_red_sum(s.x + s.y + s.z + s.w);
  __shared__ float r[4];
  if ((tid & 63) == 63) r[tid >> 6] = p;
  __syncthreads();
  if (tid == 0) {
    float s0 = (r[0] + r[1] + r[2] + r[3]) / (float)(NF * NFR);
    float P = 1.f;
#pragma unroll
    for (int e = 0; e < 3; ++e) {
      float g = fmaxf(s0 / P, 1e-5f);
      g_gP[e * 32 + bc] = g;
      g_gP[e * 32 + 16 + bc] = P;
      P *= g;
    }
  }
}

// Block-level reduction of 12 partials, 2-wave version: DPP within wave,
// one barrier, b128 LDS round-trip, double-buffered via `buf`.
__device__ __forceinline__ void block_reduce12(float* __restrict__ p,
                                               float (*red)[2][12], int buf,
                                               int lane, int wvid,
                                               float* __restrict__ s) {
#pragma unroll
  for (int k = 0; k < 12; ++k) p[k] = dpp_red_sum(p[k]);
  if (lane == 63) {
    float4* dst = reinterpret_cast<float4*>(&red[buf][wvid][0]);
    dst[0] = make_float4(p[0], p[1], p[2], p[3]);
    dst[1] = make_float4(p[4], p[5], p[6], p[7]);
    dst[2] = make_float4(p[8], p[9], p[10], p[11]);
  }
  __syncthreads();
  const float4* r = reinterpret_cast<const float4*>(&red[buf][0][0]);
#pragma unroll
  for (int k = 0; k < 3; ++k) {
    float4 a = r[k], b = r[3 + k];
    s[4 * k + 0] = a.x + b.x;
    s[4 * k + 1] = a.y + b.y;
    s[4 * k + 2] = a.z + b.z;
    s[4 * k + 3] = a.w + b.w;
  }
}

// ---------------------------------------------------------------------------
// Type-1 sweep, SRC as template param.
// Stat layout (10 live of 12 slots): [q]      num_re for c!=SRC (q = c<SRC?c:c-1)
//                                    [3+q]    num_im for c!=SRC
//                                    [6+c]    den for all c
// Diagonal numerators (c==SRC) are DEAD (v_s uses only den) -> not accumulated.
// vi[SRC]==0 is compile-time -> update for c==SRC folds to 2 fma.
// ---------------------------------------------------------------------------
template <int SRC>
__device__ __forceinline__ void t1_sweep(v2f (&xcr)[NC][4], v2f (&xci)[NC][4],
                                         v2f (&w2)[NC][4],
                                         float (&Wre)[NC][NC], float (&Wim)[NC][NC],
                                         float (*red)[2][12], int& buf,
                                         int lane, int wvid, int tid, float invN) {
  v2f p2[12];
#pragma unroll
  for (int k = 0; k < 12; ++k) p2[k] = (v2f){0.f, 0.f};
#pragma unroll
  for (int h = 0; h < 4; ++h) {
    v2f xsr = xcr[SRC][h], xsi = xci[SRC][h];
    v2f msq = xsr * xsr + xsi * xsi;
#pragma unroll
    for (int c = 0; c < NC; ++c) {
      v2f wv = w2[c][h];
      if (c != SRC) {
        const int q = (c < SRC) ? c : c - 1;
        p2[q]     += wv * (xcr[c][h] * xsr + xci[c][h] * xsi);
        p2[3 + q] += wv * (xci[c][h] * xsr - xcr[c][h] * xsi);
      }
      p2[6 + c] += wv * msq;
    }
  }
  float p[12];
#pragma unroll
  for (int k = 0; k < 12; ++k) p[k] = p2[k].x + p2[k].y;
  float s12[12];
  block_reduce12(p, red, buf, lane, wvid, s12);
  buf ^= 1;

  float vr[NC], vi[NC];
#pragma unroll
  for (int c = 0; c < NC; ++c) {
    float den = fmaxf(s12[6 + c] * invN, EPSV);
    if (c == SRC) {
      vr[c] = 1.f - __builtin_amdgcn_rsqf(den);
      vi[c] = 0.f;
    } else {
      const int q = (c < SRC) ? c : c - 1;
      float sc = invN * __builtin_amdgcn_rcpf(den);
      vr[c] = s12[q] * sc;
      vi[c] = s12[3 + q] * sc;
    }
  }
#pragma unroll
  for (int h = 0; h < 4; ++h) {
    v2f xsr = xcr[SRC][h], xsi = xci[SRC][h];
#pragma unroll
    for (int c = 0; c < NC; ++c) {
      xcr[c][h] -= xsr * vr[c] - xsi * vi[c];
      xci[c][h] -= xsi * vr[c] + xsr * vi[c];
    }
  }
  // W update parallel over 16 lanes of wave 0 (was serial in tid 0).
  // All lanes' LDS reads precede the writes in program order within the wave,
  // so reading row SRC while lane (c==SRC,j) rewrites it is race-free.
  if (tid < 16) {
    int c = tid >> 2, j = tid & 3;
    float wsr = Wre[SRC][j], wsi = Wim[SRC][j];
    float wcr = Wre[c][j],   wci = Wim[c][j];
    float vrc = (c == 0) ? vr[0] : (c == 1) ? vr[1] : (c == 2) ? vr[2] : vr[3];
    float vic = (c == 0) ? vi[0] : (c == 1) ? vi[1] : (c == 2) ? vi[2] : vi[3];
    Wre[c][j] = wcr - (vrc * wsr - vic * wsi);
    Wim[c][j] = wci - (vrc * wsi + vic * wsr);
  }
}

// ---------------------------------------------------------------------------
// Main: one block per (b,f), 128 threads (2 waves), 8 frames/thread held as
// 4x v2f pairs -> v_pk_fma_f32 codegen. Round-9 configuration — the
// measured-best of the full session map (total 193.1 us):
//  - 36 narrow (12-stat) stages: every widening/fusing alternative measured
//    worse (R4/R5 spill, R6 width-proportional cost);
//  - 2 waves/block: 4 waves (R2) +29 us, 1 wave (R7) spill+no hiding;
//  - t1 diagonal-numerator stats removed, W update 16-lane parallel (R9 cut);
//  - 3-kernel pipeline: 2-kernel folds (R10/R12/R13) all net-negative, the
//    ~70 us non-k_main time is harness-fixed (invariant across 2/3 kernels).
// CRITICAL: the type-2 src loop is `#pragma unroll 1` — round 8 proved that
// unrolling it hoists all 4 srcs' window loads (96 VGPRs) above their uses,
// blowing the 128-reg cap -> 31 MB spill writes, +60 us. One window live at
// a time keeps peak ~100 regs.
// ---------------------------------------------------------------------------
__global__ __launch_bounds__(128, 2) void k_main(const float* __restrict__ Xr,
                                                 const float* __restrict__ Xi,
                                                 float* __restrict__ out, int nout) {
  const int blk = blockIdx.x;
  const int b = blk / NF, f = blk % NF;
  const int tid = threadIdx.x;            // 0..127
  const int lane = tid & 63, wvid = tid >> 6;
  const float invN = 1.f / (float)NFR;

  __shared__ float red[2][2][12];
  __shared__ float Wre[NC][NC], Wim[NC][NC];
  __shared__ float abc[8];

  v2f xcr[NC][4], xci[NC][4];
  int rowbase[NC];
#pragma unroll
  for (int c = 0; c < NC; ++c) {
    rowbase[c] = ((b * NC + c) * NF + f) * NFR;
    const float4* pr = reinterpret_cast<const float4*>(Xr + rowbase[c]);
    const float4* pi = reinterpret_cast<const float4*>(Xi + rowbase[c]);
    float4 a0 = pr[2 * tid], a1 = pr[2 * tid + 1];
    float4 b0 = pi[2 * tid], b1 = pi[2 * tid + 1];
    xcr[c][0] = (v2f){a0.x, a0.y}; xcr[c][1] = (v2f){a0.z, a0.w};
    xcr[c][2] = (v2f){a1.x, a1.y}; xcr[c][3] = (v2f){a1.z, a1.w};
    xci[c][0] = (v2f){b0.x, b0.y}; xci[c][1] = (v2f){b0.z, b0.w};
    xci[c][2] = (v2f){b1.x, b1.y}; xci[c][3] = (v2f){b1.z, b1.w};
  }
  if (tid < 16) {
    Wre[tid >> 2][tid & 3] = ((tid >> 2) == (tid & 3)) ? 1.f : 0.f;
    Wim[tid >> 2][tid & 3] = 0.f;
  }
  // W-init visibility: ordered by the first sweep's barrier (W is first
  // read by wave-0 lanes after block_reduce12's __syncthreads).

  v2f w2[NC][4];
  int buf = 0;

  for (int e = 0; e < 3; ++e) {
    // ---- per-epoch weights: w = g * rcp(max(2*sqrt(S/P), eps)) ----
#pragma unroll
    for (int c = 0; c < NC; ++c) {
      float g = g_gP[e * 32 + b * NC + c];
      float P = g_gP[e * 32 + 16 + b * NC + c];
      float sc = __builtin_amdgcn_rcpf(P);
      const float4* ps = reinterpret_cast<const float4*>(g_S + (b * NC + c) * NFR);
      float4 S0 = ps[2 * tid], S1 = ps[2 * tid + 1];
      float sv[8] = {S0.x, S0.y, S0.z, S0.w, S1.x, S1.y, S1.z, S1.w};
      float wv[8];
#pragma unroll
      for (int j = 0; j < 8; ++j)
        wv[j] = g * __builtin_amdgcn_rcpf(fmaxf(2.f * __builtin_amdgcn_sqrtf(sv[j] * sc), EPS_MODEL));
#pragma unroll
      for (int h = 0; h < 4; ++h) w2[c][h] = (v2f){wv[2 * h], wv[2 * h + 1]};
    }

    // ================= type-1 sweeps (templated SRC) =================
    t1_sweep<0>(xcr, xci, w2, Wre, Wim, red, buf, lane, wvid, tid, invN);
    t1_sweep<1>(xcr, xci, w2, Wre, Wim, red, buf, lane, wvid, tid, invN);
    t1_sweep<2>(xcr, xci, w2, Wre, Wim, red, buf, lane, wvid, tid, invN);
    t1_sweep<3>(xcr, xci, w2, Wre, Wim, red, buf, lane, wvid, tid, invN);

    // ================= type-2 sweeps (NOT unrolled — see header note) ======
#pragma unroll 1
    for (int src = 0; src < NC; ++src) {
      const float4* pr = reinterpret_cast<const float4*>(Xr + rowbase[src]);
      const float4* pi = reinterpret_cast<const float4*>(Xi + rowbase[src]);
      // 9-frame window [8t-3 .. 8t+5] of ORIGINAL X serves both taps.
      float4 A4r = make_float4(0.f, 0.f, 0.f, 0.f), A4i = A4r;
      if (tid > 0) { A4r = pr[2 * tid - 1]; A4i = pi[2 * tid - 1]; }
      float4 B4r = pr[2 * tid], B4i = pi[2 * tid];
      float4 C4r = pr[2 * tid + 1], C4i = pi[2 * tid + 1];
      float wr[9] = {A4r.y, A4r.z, A4r.w, B4r.x, B4r.y, B4r.z, B4r.w, C4r.x, C4r.y};
      float wi[9] = {A4i.y, A4i.z, A4i.w, B4i.x, B4i.y, B4i.z, B4i.w, C4i.x, C4i.y};
#pragma unroll
      for (int tap = 0; tap < 2; ++tap) {
        v2f xs_r[4], xs_i[4];
#pragma unroll
        for (int h = 0; h < 4; ++h) {
          xs_r[h] = (v2f){wr[tap + 2 * h], wr[tap + 2 * h + 1]};
          xs_i[h] = (v2f){wi[tap + 2 * h], wi[tap + 2 * h + 1]};
        }
        v2f p2[12];
#pragma unroll
        for (int k = 0; k < 12; ++k) p2[k] = (v2f){0.f, 0.f};
#pragma unroll
        for (int h = 0; h < 4; ++h) {
          v2f xsr = xs_r[h], xsi = xs_i[h];
          v2f msq = xsr * xsr + xsi * xsi;
#pragma unroll
          for (int c = 0; c < NC; ++c) {
            v2f wv = w2[c][h];
            p2[c]     += wv * (xcr[c][h] * xsr + xci[c][h] * xsi);
            p2[4 + c] += wv * (xci[c][h] * xsr - xcr[c][h] * xsi);
            p2[8 + c] += wv * msq;
          }
        }
        float p[12];
#pragma unroll
        for (int k = 0; k < 12; ++k) p[k] = p2[k].x + p2[k].y;
        float s12[12];
        block_reduce12(p, red, buf, lane, wvid, s12);
        buf ^= 1;

        float vr[NC], vi[NC];
#pragma unroll
        for (int c = 0; c < NC; ++c) {
          float den = fmaxf(s12[8 + c], EPSV);  // SUM, not mean
          float sc = invN * __builtin_amdgcn_rcpf(den);
          vr[c] = s12[c] * sc;
          vi[c] = s12[4 + c] * sc;
        }
#pragma unroll
        for (int h = 0; h < 4; ++h) {
          v2f xsr = xs_r[h], xsi = xs_i[h];
#pragma unroll
          for (int c = 0; c < NC; ++c) {
            xcr[c][h] -= xsr * vr[c] - xsi * vi[c];
            xci[c][h] -= xsi * vr[c] + xsr * vi[c];
          }
        }
      }
    }
  }  // epochs

  // ---- solve W^T a = e1 (4x4 complex, partial pivoting), A[i][j] = W[j][i] ----
  __syncthreads();
  if (tid == 0) {
    float Ar[4][4], Ai[4][4];
    float br[4] = {1.f, 0.f, 0.f, 0.f}, bi[4] = {0.f, 0.f, 0.f, 0.f};
#pragma unroll
    for (int i = 0; i < 4; ++i)
#pragma unroll
      for (int j = 0; j < 4; ++j) {
        Ar[i][j] = Wre[j][i];
        Ai[i][j] = Wim[j][i];
      }
    for (int k = 0; k < 4; ++k) {
      int piv = k;
      float best = Ar[k][k] * Ar[k][k] + Ai[k][k] * Ai[k][k];
      for (int i = k + 1; i < 4; ++i) {
        float m = Ar[i][k] * Ar[i][k] + Ai[i][k] * Ai[i][k];
        if (m > best) { best = m; piv = i; }
      }
      if (piv != k) {
        for (int j = 0; j < 4; ++j) {
          float t = Ar[k][j]; Ar[k][j] = Ar[piv][j]; Ar[piv][j] = t;
          t = Ai[k][j]; Ai[k][j] = Ai[piv][j]; Ai[piv][j] = t;
        }
        float t = br[k]; br[k] = br[piv]; br[piv] = t;
        t = bi[k]; bi[k] = bi[piv]; bi[piv] = t;
      }
      float dr = Ar[k][k], di = Ai[k][k];
      float inv = 1.f / (dr * dr + di * di);
      for (int i = k + 1; i < 4; ++i) {
        float fr = (Ar[i][k] * dr + Ai[i][k] * di) * inv;
        float fi = (Ai[i][k] * dr - Ar[i][k] * di) * inv;
        for (int j = k; j < 4; ++j) {
          Ar[i][j] -= fr * Ar[k][j] - fi * Ai[k][j];
          Ai[i][j] -= fr * Ai[k][j] + fi * Ar[k][j];
        }
        br[i] -= fr * br[k] - fi * bi[k];
        bi[i] -= fr * bi[k] + fi * br[k];
      }
    }
    float ar[4], ai[4];
    for (int k = 3; k >= 0; --k) {
      float sr = br[k], si = bi[k];
      for (int j = k + 1; j < 4; ++j) {
        sr -= Ar[k][j] * ar[j] - Ai[k][j] * ai[j];
        si -= Ar[k][j] * ai[j] + Ai[k][j] * ar[j];
      }
      float dr = Ar[k][k], di = Ai[k][k];
      float inv = 1.f / (dr * dr + di * di);
      ar[k] = (sr * dr + si * di) * inv;
      ai[k] = (si * dr - sr * di) * inv;
    }
#pragma unroll
    for (int c = 0; c < 4; ++c) { abc[c] = ar[c]; abc[4 + c] = ai[c]; }
  }
  __syncthreads();

  // ---- output: real(Xc * a), 2x float4 per (c, thread), bounds-guarded ----
#pragma unroll
  for (int c = 0; c < NC; ++c) {
    float ar = abc[c], ai2 = abc[4 + c];
    if (rowbase[c] + 8 * tid + 7 < nout) {
      float4* po = reinterpret_cast<float4*>(out + rowbase[c]);
      v2f o0 = xcr[c][0] * ar - xci[c][0] * ai2;
      v2f o1 = xcr[c][1] * ar - xci[c][1] * ai2;
      v2f o2 = xcr[c][2] * ar - xci[c][2] * ai2;
      v2f o3 = xcr[c][3] * ar - xci[c][3] * ai2;
      po[2 * tid]     = make_float4(o0.x, o0.y, o1.x, o1.y);
      po[2 * tid + 1] = make_float4(o2.x, o2.y, o3.x, o3.y);
    }
  }
}

// ---------------------------------------------------------------------------
extern "C" void kernel_launch(void* const* d_in, const int* in_sizes, int n_in,
                              void* d_out, int out_size, void* d_ws, size_t ws_size,
                              hipStream_t stream) {
  const float* Xr = (const float*)d_in[0];
  const float* Xi = (const float*)d_in[1];
  float* out = (float*)d_out;

  dim3 g1(16, NCHUNK);
  k_colsum<<<g1, 256, 0, stream>>>(Xr, Xi);
  k_redgp<<<16, 256, 0, stream>>>();
  k_main<<<NB * NF, 128, 0, stream>>>(Xr, Xi, out, out_size);
}